// Round 1
// baseline (47.879 us; speedup 1.0000x reference)
//
#include <hip/hip_runtime.h>

// Problem constants (fixed by the reference)
#define NROWS   12288   // NUM_INPUT_ROWS
#define NCOLS   256     // CODEBOOK_DIM
#define HID     512     // HIDDEN_DIM
#define NNODES  16384   // NUM_NODES (padded row count; zeros contribute nothing to sum)

// K1: partial column sums of x over row ranges.
// x is [NROWS][NCOLS] f32 row-major. View each row as 64 float4.
// Block = 256 threads: thread t owns float4-column (t&63), row offset (t>>6).
// Each block writes its 256-float partial colsum to ws[bid*256 ..].
__global__ __launch_bounds__(256) void colsum_partial(const float* __restrict__ x,
                                                      float* __restrict__ ws,
                                                      int nblocks) {
    const int t    = threadIdx.x;
    const int c4   = t & 63;   // float4 column index 0..63
    const int rofs = t >> 6;   // 0..3
    const int bid  = blockIdx.x;
    const float4* __restrict__ x4 = (const float4*)x;

    float4 acc = make_float4(0.f, 0.f, 0.f, 0.f);
    // Grid-stride over groups of 4 rows.
    for (int r = bid * 4 + rofs; r < NROWS; r += 4 * nblocks) {
        float4 v = x4[r * 64 + c4];
        acc.x += v.x; acc.y += v.y; acc.z += v.z; acc.w += v.w;
    }

    __shared__ float4 s[256];
    s[t] = acc;
    __syncthreads();
    if (t < 64) {
        float4 a = s[t], b = s[t + 64], c = s[t + 128], d = s[t + 192];
        float4 r;
        r.x = a.x + b.x + c.x + d.x;
        r.y = a.y + b.y + c.y + d.y;
        r.z = a.z + b.z + c.z + d.z;
        r.w = a.w + b.w + c.w + d.w;
        ((float4*)ws)[bid * 64 + t] = r;
    }
}

// K2: single block, 512 threads.
// 1) reduce nblocks partial colsums -> colmean[256] (scaled by 1/NNODES)
// 2) h[t] = relu(b1[t] + sum_c colmean[c]*W1[c][t])   (W1 reads coalesced)
// 3) s = relu(dot(h, W2) + b2)   (shuffle + LDS block reduce)
// 4) broadcast s to out[16384] with float4 stores
__global__ __launch_bounds__(512) void finish_kernel(const float* __restrict__ ws,
                                                     const float* __restrict__ W1,
                                                     const float* __restrict__ b1,
                                                     const float* __restrict__ W2,
                                                     const float* __restrict__ b2,
                                                     float* __restrict__ out,
                                                     int nblocks) {
    __shared__ float colmean[NCOLS];
    __shared__ float tmp[512];
    __shared__ float warpsums[8];
    __shared__ float s_scalar;

    const int t = threadIdx.x;

    // Phase 1: reduce partials. 512 threads = 256 columns x 2 halves.
    {
        const int col  = t & 255;
        const int half = t >> 8;  // 0 or 1
        float acc = 0.f;
        for (int k = half; k < nblocks; k += 2)
            acc += ws[k * NCOLS + col];
        tmp[t] = acc;
        __syncthreads();
        if (t < NCOLS)
            colmean[t] = (tmp[t] + tmp[t + NCOLS]) * (1.0f / (float)NNODES);
        __syncthreads();
    }

    // Phase 2: hidden layer. Thread t computes h[t], t in [0,512).
    float acc = b1[t];
    #pragma unroll 8
    for (int c = 0; c < NCOLS; ++c)
        acc = fmaf(colmean[c], W1[c * HID + t], acc);
    const float h = fmaxf(acc, 0.0f);

    // Phase 3: scalar = relu(dot(h, W2) + b2)
    float p = h * W2[t];
    #pragma unroll
    for (int off = 32; off > 0; off >>= 1)
        p += __shfl_down(p, off, 64);
    if ((t & 63) == 0) warpsums[t >> 6] = p;
    __syncthreads();
    if (t == 0) {
        float s = 0.f;
        #pragma unroll
        for (int w = 0; w < 8; ++w) s += warpsums[w];
        s_scalar = fmaxf(s + b2[0], 0.0f);
    }
    __syncthreads();

    // Phase 4: broadcast to out[NNODES] (float4 = 4096 stores)
    const float val = s_scalar;
    float4 v = make_float4(val, val, val, val);
    float4* __restrict__ o4 = (float4*)out;
    #pragma unroll
    for (int i = t; i < NNODES / 4; i += 512)
        o4[i] = v;
}

extern "C" void kernel_launch(void* const* d_in, const int* in_sizes, int n_in,
                              void* d_out, int out_size, void* d_ws, size_t ws_size,
                              hipStream_t stream) {
    const float* x  = (const float*)d_in[0];
    const float* W1 = (const float*)d_in[1];
    const float* b1 = (const float*)d_in[2];
    const float* W2 = (const float*)d_in[3];
    const float* b2 = (const float*)d_in[4];
    float* out = (float*)d_out;
    float* ws  = (float*)d_ws;

    // Partial-colsum block count; bounded by available workspace (256 floats/block).
    int nblocks = 256;
    size_t need_per_block = (size_t)NCOLS * sizeof(float);
    if (ws_size < (size_t)nblocks * need_per_block) {
        nblocks = (int)(ws_size / need_per_block);
        if (nblocks < 1) nblocks = 1;   // ws_size pathologically small; still correct
    }

    colsum_partial<<<nblocks, 256, 0, stream>>>(x, ws, nblocks);
    finish_kernel<<<1, 512, 0, stream>>>(ws, W1, b1, W2, b2, out, nblocks);
}

// Round 2
// 15.467 us; speedup vs baseline: 3.0957x; 3.0957x over previous
//
#include <hip/hip_runtime.h>

// Problem constants (fixed by the reference)
#define NROWS   12288   // NUM_INPUT_ROWS
#define NCOLS   256     // CODEBOOK_DIM
#define HID     512     // HIDDEN_DIM
#define NNODES  16384   // NUM_NODES (zero-padded rows contribute nothing to the sum)

// ---------------------------------------------------------------------------
// K1: partial column sums of x. x is [NROWS][NCOLS] f32 row-major = 64 float4
// per row. Block = 256 threads: thread t owns float4-col (t&63), row offset
// (t>>6). Each block writes a 256-float partial colsum to wsA[bid*256 ..].
// ---------------------------------------------------------------------------
__global__ __launch_bounds__(256) void colsum_partial(const float* __restrict__ x,
                                                      float* __restrict__ wsA,
                                                      int nblocks) {
    const int t    = threadIdx.x;
    const int c4   = t & 63;
    const int rofs = t >> 6;
    const int bid  = blockIdx.x;
    const float4* __restrict__ x4 = (const float4*)x;

    float4 acc = make_float4(0.f, 0.f, 0.f, 0.f);
    for (int r = bid * 4 + rofs; r < NROWS; r += 4 * nblocks) {
        float4 v = x4[r * 64 + c4];
        acc.x += v.x; acc.y += v.y; acc.z += v.z; acc.w += v.w;
    }

    __shared__ float4 s[256];
    s[t] = acc;
    __syncthreads();
    if (t < 64) {
        float4 a = s[t], b = s[t + 64], c = s[t + 128], d = s[t + 192];
        float4 r;
        r.x = a.x + b.x + c.x + d.x;
        r.y = a.y + b.y + c.y + d.y;
        r.z = a.z + b.z + c.z + d.z;
        r.w = a.w + b.w + c.w + d.w;
        ((float4*)wsA)[bid * 64 + t] = r;
    }
}

// ---------------------------------------------------------------------------
// K2: 8 blocks x 512 threads. Block b owns hidden dims t = b*64 .. b*64+63.
// Phase A: every block (redundantly) reduces the nb partial colsums ->
//          colmean[256] in LDS. 512 threads = 64 float4-cols x 8 row-groups;
//          each thread does nb/8 independent float4 loads (deep ILP).
// Phase B: c-dimension split across the 8 waves: wave w handles c in
//          [w*32, w*32+32). 32 independent W1 loads per thread, LDS-combine,
//          relu, multiply by W2 chunk, wave-reduce -> one partial s per block.
// ---------------------------------------------------------------------------
__global__ __launch_bounds__(512) void hidden_kernel(const float* __restrict__ wsA,
                                                     const float* __restrict__ W1,
                                                     const float* __restrict__ b1,
                                                     const float* __restrict__ W2,
                                                     float* __restrict__ wsB,
                                                     int nb) {
    __shared__ float4 colmean4[NCOLS / 4];   // colmean[256] viewed as float4
    __shared__ float4 tmp4[512];
    __shared__ float  part[512];

    const int t = threadIdx.x;
    const int b = blockIdx.x;                // 0..7

    // ---- Phase A: colmean ----
    {
        const int c4  = t & 63;
        const int grp = t >> 6;              // 0..7
        const int per = nb >> 3;             // nb/8 partials per group
        const float4* __restrict__ wsA4 = (const float4*)wsA;

        float4 acc = make_float4(0.f, 0.f, 0.f, 0.f);
        const int k0 = grp * per;
        #pragma unroll 4
        for (int k = k0; k < k0 + per; ++k) {
            float4 v = wsA4[k * 64 + c4];
            acc.x += v.x; acc.y += v.y; acc.z += v.z; acc.w += v.w;
        }
        tmp4[t] = acc;
        __syncthreads();
        if (t < 64) {
            float4 a = tmp4[t];
            #pragma unroll
            for (int g = 1; g < 8; ++g) {
                float4 v = tmp4[g * 64 + t];
                a.x += v.x; a.y += v.y; a.z += v.z; a.w += v.w;
            }
            const float inv = 1.0f / (float)NNODES;
            a.x *= inv; a.y *= inv; a.z *= inv; a.w *= inv;
            colmean4[t] = a;
        }
        __syncthreads();
    }

    // ---- Phase B: h chunk + partial s ----
    const float* __restrict__ colmean = (const float*)colmean4;
    const int w   = t >> 6;                  // wave 0..7 -> c range
    const int l   = t & 63;                  // lane -> hidden dim within chunk
    const int myt = b * 64 + l;

    float pa = 0.f;
    const int cbase = w * 32;
    #pragma unroll
    for (int c = cbase; c < cbase + 32; ++c)
        pa = fmaf(colmean[c], W1[c * HID + myt], pa);
    part[t] = pa;
    __syncthreads();

    if (t < 64) {
        float hs = b1[myt];
        #pragma unroll
        for (int g = 0; g < 8; ++g)
            hs += part[g * 64 + l];
        const float h = fmaxf(hs, 0.0f);

        float p = h * W2[myt];
        #pragma unroll
        for (int off = 32; off > 0; off >>= 1)
            p += __shfl_down(p, off, 64);
        if (l == 0) wsB[b] = p;
    }
}

// ---------------------------------------------------------------------------
// K3: 16 blocks x 256 threads. Sum the 8 partial s (redundantly per block),
// relu(+b2), broadcast to out[16384] with float4 stores.
// ---------------------------------------------------------------------------
__global__ __launch_bounds__(256) void broadcast_kernel(const float* __restrict__ wsB,
                                                        const float* __restrict__ b2,
                                                        float* __restrict__ out) {
    __shared__ float sval;
    if (threadIdx.x == 0) {
        float s = b2[0];
        #pragma unroll
        for (int i = 0; i < 8; ++i) s += wsB[i];
        sval = fmaxf(s, 0.0f);
    }
    __syncthreads();
    const float v = sval;
    float4 f4 = make_float4(v, v, v, v);
    ((float4*)out)[blockIdx.x * 256 + threadIdx.x] = f4;
}

extern "C" void kernel_launch(void* const* d_in, const int* in_sizes, int n_in,
                              void* d_out, int out_size, void* d_ws, size_t ws_size,
                              hipStream_t stream) {
    const float* x  = (const float*)d_in[0];
    const float* W1 = (const float*)d_in[1];
    const float* b1 = (const float*)d_in[2];
    const float* W2 = (const float*)d_in[3];
    const float* b2 = (const float*)d_in[4];
    float* out = (float*)d_out;
    float* ws  = (float*)d_ws;

    // nb partial-colsum blocks (multiple of 8 for K2's 8-way split).
    int nb = 128;
    {
        size_t need = (size_t)nb * NCOLS * sizeof(float) + 8 * sizeof(float);
        if (ws_size < need) {
            nb = (int)((ws_size - 8 * sizeof(float)) / (NCOLS * sizeof(float)));
            nb &= ~7;                 // multiple of 8
            if (nb < 8) nb = 8;       // ws pathologically small; still correct
        }
    }
    float* wsA = ws;                  // nb * 256 floats
    float* wsB = ws + (size_t)nb * NCOLS;  // 8 floats

    colsum_partial<<<nb, 256, 0, stream>>>(x, wsA, nb);
    hidden_kernel<<<8, 512, 0, stream>>>(wsA, W1, b1, W2, wsB, nb);
    broadcast_kernel<<<16, 256, 0, stream>>>(wsB, b2, out);
}